// Round 1
// baseline (5256.178 us; speedup 1.0000x reference)
//
#include <hip/hip_runtime.h>
#include <hip/hip_bf16.h>

// Problem constants (B=2, S=1024, D=2048, NH=8, dqk=128, dv=256, I=8192)
#define TOKENS 2048
#define DMODEL 2048
#define SEQ    1024
#define NHEADS 8
#define QKDIM  1024
#define VDIM   2048
#define IDIM   8192

__device__ __forceinline__ float sigmoidf_(float x) { return 1.f / (1.f + expf(-x)); }
__device__ __forceinline__ float softcapf_(float x) { return 15.f * tanhf(x * (1.f / 15.f)); }
__device__ __forceinline__ float logsigf_(float x) {
  // log(sigmoid(x)), numerically stable
  return (x >= 0.f) ? -log1pf(expf(-x)) : (x - log1pf(expf(x)));
}

// ---------------------------------------------------------------------------
// Generic fp32 SGEMM: C[M,N] = A[M,K] @ B[K,N], all row-major, dims % 128 == 0.
// 128x128 tile, BK=8, 256 threads, 8x8 micro-tile.
// EPI==1: C = silu(aux) * acc   (used for act = silu(gate) * up)
// ---------------------------------------------------------------------------
template <int EPI>
__global__ __launch_bounds__(256) void sgemm_kernel(
    const float* __restrict__ A, const float* __restrict__ B,
    float* __restrict__ C, const float* __restrict__ aux,
    int M, int N, int K) {
  __shared__ float As[8][128];  // k-major (transposed) A tile
  __shared__ float Bs[8][128];
  const int tid = threadIdx.x;
  const int m0 = blockIdx.y * 128;
  const int n0 = blockIdx.x * 128;
  const int tx = tid & 15, ty = tid >> 4;
  const int arow = tid >> 1, acol = (tid & 1) * 4;
  const int brow = tid >> 5, bcol = (tid & 31) * 4;

  float acc[8][8];
#pragma unroll
  for (int i = 0; i < 8; ++i)
#pragma unroll
    for (int j = 0; j < 8; ++j) acc[i][j] = 0.f;

  for (int k0 = 0; k0 < K; k0 += 8) {
    float4 a4 = *(const float4*)&A[(size_t)(m0 + arow) * K + k0 + acol];
    float4 b4 = *(const float4*)&B[(size_t)(k0 + brow) * N + n0 + bcol];
    As[acol + 0][arow] = a4.x;
    As[acol + 1][arow] = a4.y;
    As[acol + 2][arow] = a4.z;
    As[acol + 3][arow] = a4.w;
    *(float4*)&Bs[brow][bcol] = b4;
    __syncthreads();
#pragma unroll
    for (int kk = 0; kk < 8; ++kk) {
      float a[8], b[8];
      *(float4*)&a[0] = *(const float4*)&As[kk][ty * 8];
      *(float4*)&a[4] = *(const float4*)&As[kk][ty * 8 + 4];
      *(float4*)&b[0] = *(const float4*)&Bs[kk][tx * 8];
      *(float4*)&b[4] = *(const float4*)&Bs[kk][tx * 8 + 4];
#pragma unroll
      for (int i = 0; i < 8; ++i)
#pragma unroll
        for (int j = 0; j < 8; ++j) acc[i][j] = fmaf(a[i], b[j], acc[i][j]);
    }
    __syncthreads();
  }

#pragma unroll
  for (int i = 0; i < 8; ++i) {
    const size_t r = (size_t)(m0 + ty * 8 + i);
#pragma unroll
    for (int jj = 0; jj < 8; jj += 4) {
      const size_t c = (size_t)(n0 + tx * 8 + jj);
      float4 val;
      val.x = acc[i][jj + 0];
      val.y = acc[i][jj + 1];
      val.z = acc[i][jj + 2];
      val.w = acc[i][jj + 3];
      if (EPI == 1) {
        const float4 g = *(const float4*)&aux[r * N + c];
        val.x *= g.x * sigmoidf_(g.x);
        val.y *= g.y * sigmoidf_(g.y);
        val.z *= g.z * sigmoidf_(g.z);
        val.w *= g.w * sigmoidf_(g.w);
      }
      *(float4*)&C[r * N + c] = val;
    }
  }
}

// ---------------------------------------------------------------------------
// Gate pre-activations: per token, 8 heads x {i, f}:
//   i_cap  = softcap(x . Wi[:,h] + bi[h])
//   f_ls   = log_sigmoid(softcap(x . Wf[:,h] + bf[h]))
// ---------------------------------------------------------------------------
__global__ __launch_bounds__(256) void gates_kernel(
    const float* __restrict__ x, const float* __restrict__ Wi,
    const float* __restrict__ bi, const float* __restrict__ Wf,
    const float* __restrict__ bf, float* __restrict__ icap,
    float* __restrict__ fls) {
  const int t = blockIdx.x;  // global token (b*S + s)
  const int tid = threadIdx.x;
  __shared__ float xs[2048];
  *(float4*)&xs[tid * 4] = *(const float4*)&x[(size_t)t * 2048 + tid * 4];
  *(float4*)&xs[1024 + tid * 4] =
      *(const float4*)&x[(size_t)t * 2048 + 1024 + tid * 4];
  __syncthreads();
  const int wave = tid >> 6, lane = tid & 63;
  const int b = t >> 10, s = t & 1023;
  for (int gg = wave; gg < 16; gg += 4) {
    const int head = gg >> 1;
    const int isF = gg & 1;
    const float* W = isF ? Wf : Wi;
    float acc = 0.f;
    for (int d = lane; d < 2048; d += 64) acc = fmaf(xs[d], W[d * 8 + head], acc);
#pragma unroll
    for (int m = 32; m > 0; m >>= 1) acc += __shfl_down(acc, m, 64);
    if (lane == 0) {
      const size_t o = (size_t)(b * 8 + head) * 1024 + s;
      if (isF) {
        fls[o] = logsigf_(softcapf_(acc + bf[head]));
      } else {
        icap[o] = softcapf_(acc + bi[head]);
      }
    }
  }
}

// ---------------------------------------------------------------------------
// Per-(b,h) scans over S=1024:
//   lfc  = inclusive cumsum(f_ls)
//   g    = icap - lfc
//   Mx   = inclusive cummax(g)
// ---------------------------------------------------------------------------
__global__ __launch_bounds__(1024) void scan_kernel(
    const float* __restrict__ icap, const float* __restrict__ fls,
    float* __restrict__ lfc, float* __restrict__ garr, float* __restrict__ mx) {
  const int bh = blockIdx.x;
  const int tid = threadIdx.x;
  __shared__ float sm[1024];
  sm[tid] = fls[(size_t)bh * 1024 + tid];
  __syncthreads();
  for (int off = 1; off < 1024; off <<= 1) {
    float v = sm[tid];
    if (tid >= off) v += sm[tid - off];
    __syncthreads();
    sm[tid] = v;
    __syncthreads();
  }
  const float l = sm[tid];
  lfc[(size_t)bh * 1024 + tid] = l;
  const float g = icap[(size_t)bh * 1024 + tid] - l;
  garr[(size_t)bh * 1024 + tid] = g;
  __syncthreads();
  sm[tid] = g;
  __syncthreads();
  for (int off = 1; off < 1024; off <<= 1) {
    float v = sm[tid];
    if (tid >= off) v = fmaxf(v, sm[tid - off]);
    __syncthreads();
    sm[tid] = v;
    __syncthreads();
  }
  mx[(size_t)bh * 1024 + tid] = sm[tid];
}

// ---------------------------------------------------------------------------
// mLSTM core (flash-style causal, exact — stabilizer is a prefix max):
//   w[t,s] = (q.k) * dqk^-0.5 * exp(g[s] - M[t]),  s <= t
//   n[t]   = max(|sum_s w|, exp(-(lfc[t]+M[t])))
//   h[t]   = (sum_s w v[s]) / (n + eps)
// One block per (bh, 64-row t-block); s-blocks of 32.
// ---------------------------------------------------------------------------
__global__ __launch_bounds__(256) void mlstm_kernel(
    const float* __restrict__ q, const float* __restrict__ k,
    const float* __restrict__ v, const float* __restrict__ garr,
    const float* __restrict__ lfc, const float* __restrict__ mx,
    float* __restrict__ h) {
  __shared__ float kl[32][132];  // padded: 8-row stride not 0 mod 32 banks
  __shared__ float vl[32][256];
  __shared__ float sl[64][33];
  __shared__ float gsh[32];
  const int tid = threadIdx.x;
  const int bh = blockIdx.y;
  const int b = bh >> 3, hh = bh & 7;
  const int t0 = blockIdx.x * 64;
  const int tr = tid >> 2;   // 0..63: row within t-block
  const int dg = tid & 3;    // quad: 4-way split of score cols / v dims
  const int tglob = t0 + tr;
  float acc[64];
#pragma unroll
  for (int i = 0; i < 64; ++i) acc[i] = 0.f;
  float asum = 0.f;
  const float Mt = mx[(size_t)bh * 1024 + tglob];
  const float mt = lfc[(size_t)bh * 1024 + tglob] + Mt;
  const float scale = 0.08838834764831845f;  // 128^-0.5
  const float* qrow = &q[(size_t)(b * SEQ + tglob) * 1024 + hh * 128];

  const int nsb = (t0 >> 5) + 2;  // (t0 + 64) / 32 causal s-blocks
  for (int sb = 0; sb < nsb; ++sb) {
    const int s0 = sb * 32;
    for (int idx = tid; idx < 1024; idx += 256) {
      const int rr = idx >> 5, cc = (idx & 31) << 2;
      *(float4*)&kl[rr][cc] =
          *(const float4*)&k[(size_t)(b * SEQ + s0 + rr) * 1024 + hh * 128 + cc];
    }
    for (int idx = tid; idx < 2048; idx += 256) {
      const int rr = idx >> 6, cc = (idx & 63) << 2;
      *(float4*)&vl[rr][cc] =
          *(const float4*)&v[(size_t)(b * SEQ + s0 + rr) * 2048 + hh * 256 + cc];
    }
    if (tid < 32) gsh[tid] = garr[(size_t)bh * 1024 + s0 + tid];
    __syncthreads();

    // Phase A: 64x32 score tile; thread (tr, dg) does cols s_local = dg + 4c
    float sacc[8];
#pragma unroll
    for (int c = 0; c < 8; ++c) sacc[c] = 0.f;
    for (int k4 = 0; k4 < 32; ++k4) {
      const float4 q4 = *(const float4*)&qrow[k4 << 2];
#pragma unroll
      for (int c = 0; c < 8; ++c) {
        const float4 kk4 = *(const float4*)&kl[dg + (c << 2)][k4 << 2];
        sacc[c] = fmaf(q4.x, kk4.x, sacc[c]);
        sacc[c] = fmaf(q4.y, kk4.y, sacc[c]);
        sacc[c] = fmaf(q4.z, kk4.z, sacc[c]);
        sacc[c] = fmaf(q4.w, kk4.w, sacc[c]);
      }
    }
#pragma unroll
    for (int c = 0; c < 8; ++c) {
      const int sll = dg + (c << 2);
      const int sg = s0 + sll;
      float w = 0.f;
      if (sg <= tglob) w = sacc[c] * scale * expf(gsh[sll] - Mt);
      sl[tr][sll] = w;
    }
    __syncthreads();

    // Phase B: accumulate w * v; thread owns dims d = dg*4 + 16*cc + e
    for (int s = 0; s < 32; ++s) {
      const float w = sl[tr][s];
      asum += w;
#pragma unroll
      for (int cc = 0; cc < 16; ++cc) {
        const float4 v4 = *(const float4*)&vl[s][(dg << 2) + (cc << 4)];
        acc[cc * 4 + 0] = fmaf(w, v4.x, acc[cc * 4 + 0]);
        acc[cc * 4 + 1] = fmaf(w, v4.y, acc[cc * 4 + 1]);
        acc[cc * 4 + 2] = fmaf(w, v4.z, acc[cc * 4 + 2]);
        acc[cc * 4 + 3] = fmaf(w, v4.w, acc[cc * 4 + 3]);
      }
    }
    __syncthreads();
  }

  const float n = fmaxf(fabsf(asum), expf(-mt));
  const float inv = 1.f / (n + 1e-6f);
  float* hrow = &h[(size_t)(b * SEQ + tglob) * 2048 + hh * 256];
#pragma unroll
  for (int cc = 0; cc < 16; ++cc) {
    float4 o4;
    o4.x = acc[cc * 4 + 0] * inv;
    o4.y = acc[cc * 4 + 1] * inv;
    o4.z = acc[cc * 4 + 2] * inv;
    o4.w = acc[cc * 4 + 3] * inv;
    *(float4*)&hrow[(dg << 2) + (cc << 4)] = o4;
  }
}

// ---------------------------------------------------------------------------
// Multi-head RMS (per 256-dim head) * mh_norm_w, gated by sigmoid(o_preact)
// ---------------------------------------------------------------------------
__global__ __launch_bounds__(256) void hout_kernel(
    const float* __restrict__ h, const float* __restrict__ o_pre,
    const float* __restrict__ mhw, float* __restrict__ hout) {
  const int t = blockIdx.x;
  const int tid = threadIdx.x;
  const size_t base = (size_t)t * 2048 + tid * 8;
  float vals[8];
  *(float4*)&vals[0] = *(const float4*)&h[base];
  *(float4*)&vals[4] = *(const float4*)&h[base + 4];
  float ss = 0.f;
#pragma unroll
  for (int j = 0; j < 8; ++j) ss += vals[j] * vals[j];
  // 32 consecutive threads share one head (256 dims / 8 per thread)
#pragma unroll
  for (int m = 16; m > 0; m >>= 1) ss += __shfl_xor(ss, m, 32);
  const float rinv = rsqrtf(ss * (1.f / 256.f) + 1e-6f);
  float ov[8];
  *(float4*)&ov[0] = *(const float4*)&o_pre[base];
  *(float4*)&ov[4] = *(const float4*)&o_pre[base + 4];
  float res[8];
#pragma unroll
  for (int j = 0; j < 8; ++j) {
    const float hn = vals[j] * rinv * mhw[tid * 8 + j];
    res[j] = hn * sigmoidf_(ov[j]);
  }
  *(float4*)&hout[base] = *(float4*)&res[0];
  *(float4*)&hout[base + 4] = *(float4*)&res[4];
}

// ---------------------------------------------------------------------------
// out = base + w * y * rsqrt(mean(y^2) + eps)   (row RMS over 2048)
// ---------------------------------------------------------------------------
__global__ __launch_bounds__(256) void addrms_kernel(
    const float* __restrict__ base, const float* __restrict__ y,
    const float* __restrict__ w, float* __restrict__ outp) {
  const int t = blockIdx.x;
  const int tid = threadIdx.x;
  __shared__ float red[4];
  const size_t boff = (size_t)t * 2048 + tid * 8;
  float vals[8];
  *(float4*)&vals[0] = *(const float4*)&y[boff];
  *(float4*)&vals[4] = *(const float4*)&y[boff + 4];
  float ss = 0.f;
#pragma unroll
  for (int j = 0; j < 8; ++j) ss += vals[j] * vals[j];
#pragma unroll
  for (int m = 32; m > 0; m >>= 1) ss += __shfl_xor(ss, m, 64);
  if ((tid & 63) == 0) red[tid >> 6] = ss;
  __syncthreads();
  ss = red[0] + red[1] + red[2] + red[3];
  const float rinv = rsqrtf(ss * (1.f / 2048.f) + 1e-6f);
  float bv[8];
  *(float4*)&bv[0] = *(const float4*)&base[boff];
  *(float4*)&bv[4] = *(const float4*)&base[boff + 4];
  float res[8];
#pragma unroll
  for (int j = 0; j < 8; ++j) res[j] = bv[j] + vals[j] * rinv * w[tid * 8 + j];
  *(float4*)&outp[boff] = *(float4*)&res[0];
  *(float4*)&outp[boff + 4] = *(float4*)&res[4];
}

// ---------------------------------------------------------------------------
extern "C" void kernel_launch(void* const* d_in, const int* in_sizes, int n_in,
                              void* d_out, int out_size, void* d_ws,
                              size_t ws_size, hipStream_t stream) {
  const float* x = (const float*)d_in[0];
  const float* Wq = (const float*)d_in[1];
  const float* Wk = (const float*)d_in[2];
  const float* Wv = (const float*)d_in[3];
  const float* Wo = (const float*)d_in[4];
  const float* Wi = (const float*)d_in[5];
  const float* bi = (const float*)d_in[6];
  const float* Wf = (const float*)d_in[7];
  const float* bf = (const float*)d_in[8];
  const float* mhw = (const float*)d_in[9];
  const float* Wout = (const float*)d_in[10];
  const float* rms1 = (const float*)d_in[11];
  const float* Wgate = (const float*)d_in[12];
  const float* Wup = (const float*)d_in[13];
  const float* Wdown = (const float*)d_in[14];
  const float* rms2 = (const float*)d_in[15];
  float* out = (float*)d_out;
  float* ws = (float*)d_ws;

  // workspace layout (float offsets)
  const size_t Q_OFF = 0;                    // 2048x1024
  const size_t K_OFF = 2097152;              // 2048x1024
  const size_t V_OFF = 4194304;              // 2048x2048
  const size_t O_OFF = 8388608;              // 2048x2048
  const size_t H_OFF = 12582912;             // 2048x2048
  const size_t F_OFF = 16777216;             // 2048x2048 (h1)
  const size_t G_OFF = 20971520;             // 2048x8192 (gate -> act)
  const size_t ICAP_OFF = 37748736;          // 16x1024 each below
  const size_t FLS_OFF = ICAP_OFF + 16384;
  const size_t LFC_OFF = FLS_OFF + 16384;
  const size_t GARR_OFF = LFC_OFF + 16384;
  const size_t MX_OFF = GARR_OFF + 16384;

  float* q = ws + Q_OFF;
  float* k = ws + K_OFF;
  float* v = ws + V_OFF;
  float* o = ws + O_OFF;
  float* h = ws + H_OFF;
  float* f1 = ws + F_OFF;
  float* g = ws + G_OFF;
  float* icap = ws + ICAP_OFF;
  float* fls = ws + FLS_OFF;
  float* lfc = ws + LFC_OFF;
  float* garr = ws + GARR_OFF;
  float* mxp = ws + MX_OFF;
  float* hout = ws + Q_OFF;  // reuse q+k (contiguous 2048x2048)
  float* attn = ws + V_OFF;  // reuse v
  float* mlp = ws + O_OFF;   // reuse o_preact

  const dim3 blk(256);

  // projections
  sgemm_kernel<0><<<dim3(QKDIM / 128, TOKENS / 128), blk, 0, stream>>>(
      x, Wq, q, nullptr, TOKENS, QKDIM, DMODEL);
  sgemm_kernel<0><<<dim3(QKDIM / 128, TOKENS / 128), blk, 0, stream>>>(
      x, Wk, k, nullptr, TOKENS, QKDIM, DMODEL);
  sgemm_kernel<0><<<dim3(VDIM / 128, TOKENS / 128), blk, 0, stream>>>(
      x, Wv, v, nullptr, TOKENS, VDIM, DMODEL);
  sgemm_kernel<0><<<dim3(VDIM / 128, TOKENS / 128), blk, 0, stream>>>(
      x, Wo, o, nullptr, TOKENS, VDIM, DMODEL);

  // gates + scans
  gates_kernel<<<TOKENS, blk, 0, stream>>>(x, Wi, bi, Wf, bf, icap, fls);
  scan_kernel<<<16, 1024, 0, stream>>>(icap, fls, lfc, garr, mxp);

  // mLSTM core
  mlstm_kernel<<<dim3(16, 16), blk, 0, stream>>>(q, k, v, garr, lfc, mxp, h);

  // multi-head norm + output gate
  hout_kernel<<<TOKENS, blk, 0, stream>>>(h, o, mhw, hout);

  // attention output projection
  sgemm_kernel<0><<<dim3(VDIM / 128, TOKENS / 128), blk, 0, stream>>>(
      hout, Wout, attn, nullptr, TOKENS, DMODEL, VDIM);

  // h1 = x + rms_norm(attn, rms1_w)
  addrms_kernel<<<TOKENS, blk, 0, stream>>>(x, attn, rms1, f1);

  // MLP: gate GEMM, then up GEMM with fused silu(gate)*up epilogue into G
  sgemm_kernel<0><<<dim3(IDIM / 128, TOKENS / 128), blk, 0, stream>>>(
      f1, Wgate, g, nullptr, TOKENS, IDIM, DMODEL);
  sgemm_kernel<1><<<dim3(IDIM / 128, TOKENS / 128), blk, 0, stream>>>(
      f1, Wup, g, g, TOKENS, IDIM, DMODEL);
  sgemm_kernel<0><<<dim3(DMODEL / 128, TOKENS / 128), blk, 0, stream>>>(
      g, Wdown, mlp, nullptr, TOKENS, DMODEL, IDIM);

  // out = h1 + rms_norm(mlp, rms2_w)
  addrms_kernel<<<TOKENS, blk, 0, stream>>>(f1, mlp, rms2, out);
}

// Round 2
// 1194.298 us; speedup vs baseline: 4.4011x; 4.4011x over previous
//
#include <hip/hip_runtime.h>
#include <hip/hip_bf16.h>

// B=2, S=1024, D=2048, NH=8, dqk=128, dv=256, I=8192
#define TOKENS 2048
#define DMODEL 2048
#define SEQ    1024
#define QKSTR  2048   // fused q|k buffer row stride
#define VOSTR  4096   // fused v|o buffer row stride

typedef __attribute__((ext_vector_type(8))) short bf16x8;
typedef __attribute__((ext_vector_type(4))) float f32x4;
typedef __attribute__((ext_vector_type(8))) unsigned short u16x8;
typedef __attribute__((ext_vector_type(4))) unsigned short u16x4;

__device__ __forceinline__ float sigmoidf_(float x) { return 1.f / (1.f + expf(-x)); }
__device__ __forceinline__ float softcapf_(float x) { return 15.f * tanhf(x * (1.f / 15.f)); }
__device__ __forceinline__ float logsigf_(float x) {
  return (x >= 0.f) ? -log1pf(expf(-x)) : (x - log1pf(expf(x)));
}
__device__ __forceinline__ unsigned short f2bf(float f) {  // RNE, inputs finite
  unsigned u = __builtin_bit_cast(unsigned, f);
  u += 0x7FFFu + ((u >> 16) & 1u);
  return (unsigned short)(u >> 16);
}
__device__ __forceinline__ float bf2f(unsigned short b) {
  unsigned u = ((unsigned)b) << 16;
  return __builtin_bit_cast(float, u);
}

typedef __attribute__((address_space(3))) void lds_void;
typedef const __attribute__((address_space(1))) void gmem_void;
__device__ __forceinline__ void gload16(const void* g, void* l) {
  __builtin_amdgcn_global_load_lds((gmem_void*)g, (lds_void*)l, 16, 0, 0);
}

// ---------------------------------------------------------------------------
// bf16 MFMA GEMM (m97 structure): C[M,N] = A[M,K] @ BT[N,K]^T
// 128x128 tile, BK=32, 256 threads = 4 waves (2x2), 4x4 16x16x32 fragments.
// EPI 0: fp32 out.  EPI 1: bf16 out.  EPI 2: bf16 out = silu(aux)*acc.
// ---------------------------------------------------------------------------
template <int EPI>
__global__ __launch_bounds__(256) void gemm_bf16(
    const unsigned short* __restrict__ A, const unsigned short* __restrict__ BT,
    void* __restrict__ Cout, const unsigned short* __restrict__ aux,
    int M, int N, int K) {
  __shared__ unsigned short As[128 * 32];
  __shared__ unsigned short Bs[128 * 32];
  const int tid = threadIdx.x;
  const int m0 = blockIdx.y * 128;
  const int n0 = blockIdx.x * 128;
  const int wid = tid >> 6;
  const int lane = tid & 63;
  const int wr = wid >> 1, wc = wid & 1;
  const int fr = lane & 15, fq = lane >> 4;

  const f32x4 zero = {0.f, 0.f, 0.f, 0.f};
  f32x4 acc[4][4];
#pragma unroll
  for (int m = 0; m < 4; ++m)
#pragma unroll
    for (int n = 0; n < 4; ++n) acc[m][n] = zero;

  // staging: LDS linear [128][32] bf16; thread t covers bytes [t*16, t*16+16)
  // of the first 64 rows and the same of rows 64..127.
  const int srow = tid >> 2;          // row 0..63
  const int scol = (tid & 3) * 8;     // k element 0/8/16/24
  const unsigned short* Ag0 = A + (size_t)(m0 + srow) * K + scol;
  const unsigned short* Ag1 = A + (size_t)(m0 + 64 + srow) * K + scol;
  const unsigned short* Bg0 = BT + (size_t)(n0 + srow) * K + scol;
  const unsigned short* Bg1 = BT + (size_t)(n0 + 64 + srow) * K + scol;
  unsigned short* lA0 = &As[tid * 8];
  unsigned short* lA1 = &As[2048 + tid * 8];
  unsigned short* lB0 = &Bs[tid * 8];
  unsigned short* lB1 = &Bs[2048 + tid * 8];

  for (int k0 = 0; k0 < K; k0 += 32) {
    gload16(Ag0 + k0, lA0);
    gload16(Ag1 + k0, lA1);
    gload16(Bg0 + k0, lB0);
    gload16(Bg1 + k0, lB1);
    __syncthreads();  // drains vmcnt before barrier

    bf16x8 af[4], bfm[4];
#pragma unroll
    for (int m = 0; m < 4; ++m)
      af[m] = *(const bf16x8*)&As[(wr * 64 + m * 16 + fr) * 32 + fq * 8];
#pragma unroll
    for (int n = 0; n < 4; ++n)
      bfm[n] = *(const bf16x8*)&Bs[(wc * 64 + n * 16 + fr) * 32 + fq * 8];
#pragma unroll
    for (int m = 0; m < 4; ++m)
#pragma unroll
      for (int n = 0; n < 4; ++n)
        acc[m][n] = __builtin_amdgcn_mfma_f32_16x16x32_bf16(af[m], bfm[n],
                                                            acc[m][n], 0, 0, 0);
    __syncthreads();
  }

  // C/D layout: col = lane&15, row = (lane>>4)*4 + reg  [m89/m91 verified]
  const int orow = m0 + wr * 64 + fq * 4;
  const int ocol = n0 + wc * 64 + fr;
#pragma unroll
  for (int m = 0; m < 4; ++m) {
#pragma unroll
    for (int n = 0; n < 4; ++n) {
      const int cc = ocol + n * 16;
#pragma unroll
      for (int j = 0; j < 4; ++j) {
        const size_t idx = (size_t)(orow + m * 16 + j) * N + cc;
        float v = acc[m][n][j];
        if (EPI == 0) {
          ((float*)Cout)[idx] = v;
        } else {
          if (EPI == 2) {
            const float gv = bf2f(aux[idx]);
            v *= gv * sigmoidf_(gv);  // silu(gate) * up
          }
          ((unsigned short*)Cout)[idx] = f2bf(v);
        }
      }
    }
  }
}

// ---------------------------------------------------------------------------
// fp32 -> bf16 flat cast (n % 2048 == 0); one block per 2048 elements
// ---------------------------------------------------------------------------
__global__ __launch_bounds__(256) void castf2b_kernel(
    const float* __restrict__ in, unsigned short* __restrict__ outp) {
  const size_t i = ((size_t)blockIdx.x * 256 + threadIdx.x) * 8;
  float4 a = *(const float4*)&in[i];
  float4 b = *(const float4*)&in[i + 4];
  u16x8 o;
  o[0] = f2bf(a.x); o[1] = f2bf(a.y); o[2] = f2bf(a.z); o[3] = f2bf(a.w);
  o[4] = f2bf(b.x); o[5] = f2bf(b.y); o[6] = f2bf(b.z); o[7] = f2bf(b.w);
  *(u16x8*)&outp[i] = o;
}

// ---------------------------------------------------------------------------
// fp32 [K][N] -> bf16 [N][K] transpose-cast, 32x32 LDS tiles
// ---------------------------------------------------------------------------
__global__ __launch_bounds__(256) void castT_kernel(
    const float* __restrict__ W, unsigned short* __restrict__ WT, int K, int N) {
  __shared__ float tile[32][33];
  const int n0 = blockIdx.x * 32, k0 = blockIdx.y * 32;
  const int r = threadIdx.x >> 3;
  const int c4 = (threadIdx.x & 7) * 4;
  float4 v = *(const float4*)&W[(size_t)(k0 + r) * N + n0 + c4];
  tile[r][c4 + 0] = v.x; tile[r][c4 + 1] = v.y;
  tile[r][c4 + 2] = v.z; tile[r][c4 + 3] = v.w;
  __syncthreads();
  u16x4 o;
  o[0] = f2bf(tile[c4 + 0][r]); o[1] = f2bf(tile[c4 + 1][r]);
  o[2] = f2bf(tile[c4 + 2][r]); o[3] = f2bf(tile[c4 + 3][r]);
  *(u16x4*)&WT[(size_t)(n0 + r) * K + k0 + c4] = o;
}

// ---------------------------------------------------------------------------
// Gate pre-activations (fp32): i_cap, f_ls = logsig(softcap(...))
// ---------------------------------------------------------------------------
__global__ __launch_bounds__(256) void gates_kernel(
    const float* __restrict__ x, const float* __restrict__ Wi,
    const float* __restrict__ bi, const float* __restrict__ Wf,
    const float* __restrict__ bf, float* __restrict__ icap,
    float* __restrict__ fls) {
  const int t = blockIdx.x;
  const int tid = threadIdx.x;
  __shared__ float xs[2048];
  *(float4*)&xs[tid * 4] = *(const float4*)&x[(size_t)t * 2048 + tid * 4];
  *(float4*)&xs[1024 + tid * 4] =
      *(const float4*)&x[(size_t)t * 2048 + 1024 + tid * 4];
  __syncthreads();
  const int wave = tid >> 6, lane = tid & 63;
  const int b = t >> 10, s = t & 1023;
  for (int gg = wave; gg < 16; gg += 4) {
    const int head = gg >> 1;
    const int isF = gg & 1;
    const float* W = isF ? Wf : Wi;
    float acc = 0.f;
    for (int d = lane; d < 2048; d += 64) acc = fmaf(xs[d], W[d * 8 + head], acc);
#pragma unroll
    for (int m = 32; m > 0; m >>= 1) acc += __shfl_down(acc, m, 64);
    if (lane == 0) {
      const size_t o = (size_t)(b * 8 + head) * 1024 + s;
      if (isF) fls[o] = logsigf_(softcapf_(acc + bf[head]));
      else icap[o] = softcapf_(acc + bi[head]);
    }
  }
}

// ---------------------------------------------------------------------------
// Per-(b,h) scans: lfc = cumsum(fls); g = icap - lfc; mx = cummax(g)
// ---------------------------------------------------------------------------
__global__ __launch_bounds__(1024) void scan_kernel(
    const float* __restrict__ icap, const float* __restrict__ fls,
    float* __restrict__ lfc, float* __restrict__ garr, float* __restrict__ mx) {
  const int bh = blockIdx.x;
  const int tid = threadIdx.x;
  __shared__ float sm[1024];
  sm[tid] = fls[(size_t)bh * 1024 + tid];
  __syncthreads();
  for (int off = 1; off < 1024; off <<= 1) {
    float v = sm[tid];
    if (tid >= off) v += sm[tid - off];
    __syncthreads();
    sm[tid] = v;
    __syncthreads();
  }
  const float l = sm[tid];
  lfc[(size_t)bh * 1024 + tid] = l;
  const float g = icap[(size_t)bh * 1024 + tid] - l;
  garr[(size_t)bh * 1024 + tid] = g;
  __syncthreads();
  sm[tid] = g;
  __syncthreads();
  for (int off = 1; off < 1024; off <<= 1) {
    float v = sm[tid];
    if (tid >= off) v = fmaxf(v, sm[tid - off]);
    __syncthreads();
    sm[tid] = v;
    __syncthreads();
  }
  mx[(size_t)bh * 1024 + tid] = sm[tid];
}

// ---------------------------------------------------------------------------
// mLSTM core (fp32 flash-style, exact stabilizer = prefix max)
// qk buffer: [token][2048] (q cols 0..1023, k cols 1024..2047)
// vo buffer: [token][4096] (v cols 0..2047, o cols 2048..4095)
// ---------------------------------------------------------------------------
__global__ __launch_bounds__(256) void mlstm_kernel(
    const float* __restrict__ qk, const float* __restrict__ vo,
    const float* __restrict__ garr, const float* __restrict__ lfc,
    const float* __restrict__ mx, float* __restrict__ h) {
  __shared__ float kl[32][132];
  __shared__ float vl[32][256];
  __shared__ float sl[64][33];
  __shared__ float gsh[32];
  const int tid = threadIdx.x;
  const int bh = blockIdx.y;
  const int b = bh >> 3, hh = bh & 7;
  const int t0 = blockIdx.x * 64;
  const int tr = tid >> 2;
  const int dg = tid & 3;
  const int tglob = t0 + tr;
  float acc[64];
#pragma unroll
  for (int i = 0; i < 64; ++i) acc[i] = 0.f;
  float asum = 0.f;
  const float Mt = mx[(size_t)bh * 1024 + tglob];
  const float mt = lfc[(size_t)bh * 1024 + tglob] + Mt;
  const float scale = 0.08838834764831845f;  // 128^-0.5
  const float* qrow = &qk[(size_t)(b * SEQ + tglob) * QKSTR + hh * 128];

  const int nsb = (t0 >> 5) + 2;
  for (int sb = 0; sb < nsb; ++sb) {
    const int s0 = sb * 32;
    for (int idx = tid; idx < 1024; idx += 256) {
      const int rr = idx >> 5, cc = (idx & 31) << 2;
      *(float4*)&kl[rr][cc] = *(const float4*)
          &qk[(size_t)(b * SEQ + s0 + rr) * QKSTR + 1024 + hh * 128 + cc];
    }
    for (int idx = tid; idx < 2048; idx += 256) {
      const int rr = idx >> 6, cc = (idx & 63) << 2;
      *(float4*)&vl[rr][cc] = *(const float4*)
          &vo[(size_t)(b * SEQ + s0 + rr) * VOSTR + hh * 256 + cc];
    }
    if (tid < 32) gsh[tid] = garr[(size_t)bh * 1024 + s0 + tid];
    __syncthreads();

    float sacc[8];
#pragma unroll
    for (int c = 0; c < 8; ++c) sacc[c] = 0.f;
    for (int k4 = 0; k4 < 32; ++k4) {
      const float4 q4 = *(const float4*)&qrow[k4 << 2];
#pragma unroll
      for (int c = 0; c < 8; ++c) {
        const float4 kk4 = *(const float4*)&kl[dg + (c << 2)][k4 << 2];
        sacc[c] = fmaf(q4.x, kk4.x, sacc[c]);
        sacc[c] = fmaf(q4.y, kk4.y, sacc[c]);
        sacc[c] = fmaf(q4.z, kk4.z, sacc[c]);
        sacc[c] = fmaf(q4.w, kk4.w, sacc[c]);
      }
    }
#pragma unroll
    for (int c = 0; c < 8; ++c) {
      const int sll = dg + (c << 2);
      const int sg = s0 + sll;
      float w = 0.f;
      if (sg <= tglob) w = sacc[c] * scale * expf(gsh[sll] - Mt);
      sl[tr][sll] = w;
    }
    __syncthreads();

    for (int s = 0; s < 32; ++s) {
      const float w = sl[tr][s];
      asum += w;
#pragma unroll
      for (int cc = 0; cc < 16; ++cc) {
        const float4 v4 = *(const float4*)&vl[s][(dg << 2) + (cc << 4)];
        acc[cc * 4 + 0] = fmaf(w, v4.x, acc[cc * 4 + 0]);
        acc[cc * 4 + 1] = fmaf(w, v4.y, acc[cc * 4 + 1]);
        acc[cc * 4 + 2] = fmaf(w, v4.z, acc[cc * 4 + 2]);
        acc[cc * 4 + 3] = fmaf(w, v4.w, acc[cc * 4 + 3]);
      }
    }
    __syncthreads();
  }

  const float n = fmaxf(fabsf(asum), expf(-mt));
  const float inv = 1.f / (n + 1e-6f);
  float* hrow = &h[(size_t)(b * SEQ + tglob) * 2048 + hh * 256];
#pragma unroll
  for (int cc = 0; cc < 16; ++cc) {
    float4 o4;
    o4.x = acc[cc * 4 + 0] * inv;
    o4.y = acc[cc * 4 + 1] * inv;
    o4.z = acc[cc * 4 + 2] * inv;
    o4.w = acc[cc * 4 + 3] * inv;
    *(float4*)&hrow[(dg << 2) + (cc << 4)] = o4;
  }
}

// ---------------------------------------------------------------------------
// Multi-head RMS * mh_norm_w, gated by sigmoid(o_preact) -> bf16
// ---------------------------------------------------------------------------
__global__ __launch_bounds__(256) void hout_kernel(
    const float* __restrict__ h, const float* __restrict__ vo,
    const float* __restrict__ mhw, unsigned short* __restrict__ houtb) {
  const int t = blockIdx.x;
  const int tid = threadIdx.x;
  float vals[8];
  *(float4*)&vals[0] = *(const float4*)&h[(size_t)t * 2048 + tid * 8];
  *(float4*)&vals[4] = *(const float4*)&h[(size_t)t * 2048 + tid * 8 + 4];
  float ss = 0.f;
#pragma unroll
  for (int j = 0; j < 8; ++j) ss += vals[j] * vals[j];
#pragma unroll
  for (int m = 16; m > 0; m >>= 1) ss += __shfl_xor(ss, m, 32);
  const float rinv = rsqrtf(ss * (1.f / 256.f) + 1e-6f);
  float ov[8];
  const size_t obase = (size_t)t * VOSTR + 2048 + tid * 8;
  *(float4*)&ov[0] = *(const float4*)&vo[obase];
  *(float4*)&ov[4] = *(const float4*)&vo[obase + 4];
  u16x8 res;
#pragma unroll
  for (int j = 0; j < 8; ++j) {
    const float hn = vals[j] * rinv * mhw[tid * 8 + j];
    res[j] = f2bf(hn * sigmoidf_(ov[j]));
  }
  *(u16x8*)&houtb[(size_t)t * 2048 + tid * 8] = res;
}

// ---------------------------------------------------------------------------
// out = base + w * y * rsqrt(mean(y^2)+eps); optional bf16 copy of out
// ---------------------------------------------------------------------------
template <int EMIT_BF16>
__global__ __launch_bounds__(256) void addrms_kernel(
    const float* __restrict__ base_, const float* __restrict__ y,
    const float* __restrict__ w, float* __restrict__ outp,
    unsigned short* __restrict__ outb) {
  const int t = blockIdx.x;
  const int tid = threadIdx.x;
  __shared__ float red[4];
  const size_t boff = (size_t)t * 2048 + tid * 8;
  float vals[8];
  *(float4*)&vals[0] = *(const float4*)&y[boff];
  *(float4*)&vals[4] = *(const float4*)&y[boff + 4];
  float ss = 0.f;
#pragma unroll
  for (int j = 0; j < 8; ++j) ss += vals[j] * vals[j];
#pragma unroll
  for (int m = 32; m > 0; m >>= 1) ss += __shfl_xor(ss, m, 64);
  if ((tid & 63) == 0) red[tid >> 6] = ss;
  __syncthreads();
  ss = red[0] + red[1] + red[2] + red[3];
  const float rinv = rsqrtf(ss * (1.f / 2048.f) + 1e-6f);
  float bv[8];
  *(float4*)&bv[0] = *(const float4*)&base_[boff];
  *(float4*)&bv[4] = *(const float4*)&base_[boff + 4];
  float res[8];
  u16x8 rb;
#pragma unroll
  for (int j = 0; j < 8; ++j) {
    res[j] = bv[j] + vals[j] * rinv * w[tid * 8 + j];
    if (EMIT_BF16) rb[j] = f2bf(res[j]);
  }
  *(float4*)&outp[boff] = *(float4*)&res[0];
  *(float4*)&outp[boff + 4] = *(float4*)&res[4];
  if (EMIT_BF16) *(u16x8*)&outb[boff] = rb;
}

// ---------------------------------------------------------------------------
extern "C" void kernel_launch(void* const* d_in, const int* in_sizes, int n_in,
                              void* d_out, int out_size, void* d_ws,
                              size_t ws_size, hipStream_t stream) {
  const float* x = (const float*)d_in[0];
  const float* Wq = (const float*)d_in[1];
  const float* Wk = (const float*)d_in[2];
  const float* Wv = (const float*)d_in[3];
  const float* Wo = (const float*)d_in[4];
  const float* Wi = (const float*)d_in[5];
  const float* bi = (const float*)d_in[6];
  const float* Wf = (const float*)d_in[7];
  const float* bf = (const float*)d_in[8];
  const float* mhw = (const float*)d_in[9];
  const float* Wout = (const float*)d_in[10];
  const float* rms1 = (const float*)d_in[11];
  const float* Wgate = (const float*)d_in[12];
  const float* Wup = (const float*)d_in[13];
  const float* Wdown = (const float*)d_in[14];
  const float* rms2 = (const float*)d_in[15];
  float* out = (float*)d_out;
  char* base = (char*)d_ws;
  const size_t MBy = 1024 * 1024;

  // Workspace layout (byte offsets, MB). Single-stream order makes reuse safe:
  //  0.. 32  W     : per-GEMM transposed bf16 weights (reused 6x)
  // 32.. 40  xb    : bf16 x                -> later f1b (after vo GEMM)
  // 40.. 56  qk    : fp32 q|k              -> later mlp (after mlstm)
  // 56.. 88  vo    : fp32 v|o              -> later g bf16 (after hout)
  // 88..104  h     : fp32 mlstm out        \
  //104..112  houtb : bf16                   } actb bf16 88..120 (after attn+rms1)
  //112..128  attn  : fp32                  /
  //128..144  f1    : fp32 residual
  //144..145  gate scalars (icap, fls, lfc, garr, mx)
  unsigned short* W = (unsigned short*)(base);
  unsigned short* xb = (unsigned short*)(base + 32 * MBy);
  float* qk = (float*)(base + 40 * MBy);
  float* vo = (float*)(base + 56 * MBy);
  float* h = (float*)(base + 88 * MBy);
  unsigned short* houtb = (unsigned short*)(base + 104 * MBy);
  float* attn = (float*)(base + 112 * MBy);
  float* f1 = (float*)(base + 128 * MBy);
  unsigned short* f1b = (unsigned short*)(base + 32 * MBy);
  unsigned short* gbuf = (unsigned short*)(base + 56 * MBy);
  unsigned short* actb = (unsigned short*)(base + 88 * MBy);
  float* mlp = (float*)(base + 40 * MBy);
  float* gs = (float*)(base + 144 * MBy);
  float* icap = gs;
  float* fls = gs + 16384;
  float* lfc = gs + 32768;
  float* garr = gs + 49152;
  float* mxp = gs + 65536;

  const dim3 blk(256);

  // x -> bf16; gate preacts + scans (independent of GEMMs)
  castf2b_kernel<<<TOKENS, blk, 0, stream>>>(x, xb);
  gates_kernel<<<TOKENS, blk, 0, stream>>>(x, Wi, bi, Wf, bf, icap, fls);
  scan_kernel<<<16, 1024, 0, stream>>>(icap, fls, lfc, garr, mxp);

  // qk = xb @ [Wq|Wk]
  castT_kernel<<<dim3(1024 / 32, 2048 / 32), blk, 0, stream>>>(Wq, W, 2048, 1024);
  castT_kernel<<<dim3(1024 / 32, 2048 / 32), blk, 0, stream>>>(Wk, W + 1024 * 2048, 2048, 1024);
  gemm_bf16<0><<<dim3(16, 16), blk, 0, stream>>>(xb, W, qk, nullptr, TOKENS, 2048, 2048);

  // vo = xb @ [Wv|Wo]
  castT_kernel<<<dim3(2048 / 32, 2048 / 32), blk, 0, stream>>>(Wv, W, 2048, 2048);
  castT_kernel<<<dim3(2048 / 32, 2048 / 32), blk, 0, stream>>>(Wo, W + 2048 * 2048, 2048, 2048);
  gemm_bf16<0><<<dim3(32, 16), blk, 0, stream>>>(xb, W, vo, nullptr, TOKENS, 4096, 2048);

  // mLSTM core + multi-head norm + output gate
  mlstm_kernel<<<dim3(16, 16), blk, 0, stream>>>(qk, vo, garr, lfc, mxp, h);
  hout_kernel<<<TOKENS, blk, 0, stream>>>(h, vo, mhw, houtb);

  // attn = houtb @ Wout
  castT_kernel<<<dim3(2048 / 32, 2048 / 32), blk, 0, stream>>>(Wout, W, 2048, 2048);
  gemm_bf16<0><<<dim3(16, 16), blk, 0, stream>>>(houtb, W, attn, nullptr, TOKENS, 2048, 2048);

  // f1 = x + rms(attn); also bf16 copy
  addrms_kernel<1><<<TOKENS, blk, 0, stream>>>(x, attn, rms1, f1, f1b);

  // gate GEMM (bf16 out), then up GEMM with fused silu(gate)*up -> actb bf16
  castT_kernel<<<dim3(8192 / 32, 2048 / 32), blk, 0, stream>>>(Wgate, W, 2048, 8192);
  gemm_bf16<1><<<dim3(64, 16), blk, 0, stream>>>(f1b, W, gbuf, nullptr, TOKENS, 8192, 2048);
  castT_kernel<<<dim3(8192 / 32, 2048 / 32), blk, 0, stream>>>(Wup, W, 2048, 8192);
  gemm_bf16<2><<<dim3(64, 16), blk, 0, stream>>>(f1b, W, actb, gbuf, TOKENS, 8192, 2048);

  // mlp = actb @ Wdown
  castT_kernel<<<dim3(2048 / 32, 8192 / 32), blk, 0, stream>>>(Wdown, W, 8192, 2048);
  gemm_bf16<0><<<dim3(16, 16), blk, 0, stream>>>(actb, W, mlp, nullptr, TOKENS, 2048, 8192);

  // out = f1 + rms(mlp)
  addrms_kernel<0><<<TOKENS, blk, 0, stream>>>(f1, mlp, rms2, out, nullptr);
}

// Round 3
// 836.575 us; speedup vs baseline: 6.2830x; 1.4276x over previous
//
#include <hip/hip_runtime.h>
#include <hip/hip_bf16.h>

// B=2, S=1024, D=2048, NH=8, dqk=128, dv=256, I=8192
#define TOKENS 2048
#define DMODEL 2048
#define SEQ    1024

typedef __attribute__((ext_vector_type(8))) short bf16x8;
typedef __attribute__((ext_vector_type(4))) short bf16x4;
typedef __attribute__((ext_vector_type(4))) float f32x4;
typedef __attribute__((ext_vector_type(8))) unsigned short u16x8;
typedef __attribute__((ext_vector_type(4))) unsigned short u16x4;

__device__ __forceinline__ float sigmoidf_(float x) { return 1.f / (1.f + expf(-x)); }
__device__ __forceinline__ float softcapf_(float x) { return 15.f * tanhf(x * (1.f / 15.f)); }
__device__ __forceinline__ float logsigf_(float x) {
  return (x >= 0.f) ? -log1pf(expf(-x)) : (x - log1pf(expf(x)));
}
__device__ __forceinline__ unsigned short f2bf(float f) {  // RNE, inputs finite
  unsigned u = __builtin_bit_cast(unsigned, f);
  u += 0x7FFFu + ((u >> 16) & 1u);
  return (unsigned short)(u >> 16);
}
__device__ __forceinline__ float bf2f(unsigned short b) {
  unsigned u = ((unsigned)b) << 16;
  return __builtin_bit_cast(float, u);
}

typedef __attribute__((address_space(3))) void lds_void;
typedef const __attribute__((address_space(1))) void gmem_void;
__device__ __forceinline__ void gload16(const void* g, void* l) {
  __builtin_amdgcn_global_load_lds((gmem_void*)g, (lds_void*)l, 16, 0, 0);
}
__device__ __forceinline__ unsigned lds_off(const void* p) {
  return (unsigned)(size_t)(__attribute__((address_space(3))) const void*)p;
}

#if defined(__has_builtin)
#if __has_builtin(__builtin_amdgcn_mfma_f32_16x16x16bf16_1k)
#define HAVE_MFMA16 1
#endif
#endif

__device__ __forceinline__ f32x4 mfma16_bf16(bf16x4 a, bf16x4 b, f32x4 c) {
#ifdef HAVE_MFMA16
  return __builtin_amdgcn_mfma_f32_16x16x16bf16_1k(a, b, c, 0, 0, 0);
#else
  f32x4 d;
  asm volatile("v_mfma_f32_16x16x16_bf16 %0, %1, %2, %3"
               : "=v"(d) : "v"(a), "v"(b), "v"(c));
  return d;
#endif
}

__device__ __forceinline__ bf16x4 tr_read(unsigned addr) {
  bf16x4 d;
  asm volatile("ds_read_b64_tr_b16 %0, %1" : "=v"(d) : "v"(addr));
  return d;
}

// ---------------------------------------------------------------------------
// bf16 MFMA GEMM (m97 structure): C[M,N] = A[M,K] @ BT[N,K]^T
// 128x128 tile, BK=32, 256 threads = 4 waves (2x2), 4x4 16x16x32 fragments.
// EPI 0: fp32 out. EPI 1: bf16 out. EPI 2: bf16 out = silu(aux)*acc.
// EPI 3: split — cols <2048 bf16 -> Cout (stride 2048); cols >=2048 fp32 ->
//        Cout2 (stride 2048).
// ---------------------------------------------------------------------------
template <int EPI>
__global__ __launch_bounds__(256) void gemm_bf16(
    const unsigned short* __restrict__ A, const unsigned short* __restrict__ BT,
    void* __restrict__ Cout, void* __restrict__ Cout2,
    const unsigned short* __restrict__ aux, int M, int N, int K) {
  __shared__ unsigned short As[128 * 32];
  __shared__ unsigned short Bs[128 * 32];
  const int tid = threadIdx.x;
  const int m0 = blockIdx.y * 128;
  const int n0 = blockIdx.x * 128;
  const int wid = tid >> 6;
  const int lane = tid & 63;
  const int wr = wid >> 1, wc = wid & 1;
  const int fr = lane & 15, fq = lane >> 4;

  const f32x4 zero = {0.f, 0.f, 0.f, 0.f};
  f32x4 acc[4][4];
#pragma unroll
  for (int m = 0; m < 4; ++m)
#pragma unroll
    for (int n = 0; n < 4; ++n) acc[m][n] = zero;

  const int srow = tid >> 2;
  const int scol = (tid & 3) * 8;
  const unsigned short* Ag0 = A + (size_t)(m0 + srow) * K + scol;
  const unsigned short* Ag1 = A + (size_t)(m0 + 64 + srow) * K + scol;
  const unsigned short* Bg0 = BT + (size_t)(n0 + srow) * K + scol;
  const unsigned short* Bg1 = BT + (size_t)(n0 + 64 + srow) * K + scol;
  unsigned short* lA0 = &As[tid * 8];
  unsigned short* lA1 = &As[2048 + tid * 8];
  unsigned short* lB0 = &Bs[tid * 8];
  unsigned short* lB1 = &Bs[2048 + tid * 8];

  for (int k0 = 0; k0 < K; k0 += 32) {
    gload16(Ag0 + k0, lA0);
    gload16(Ag1 + k0, lA1);
    gload16(Bg0 + k0, lB0);
    gload16(Bg1 + k0, lB1);
    __syncthreads();

    bf16x8 af[4], bfm[4];
#pragma unroll
    for (int m = 0; m < 4; ++m)
      af[m] = *(const bf16x8*)&As[(wr * 64 + m * 16 + fr) * 32 + fq * 8];
#pragma unroll
    for (int n = 0; n < 4; ++n)
      bfm[n] = *(const bf16x8*)&Bs[(wc * 64 + n * 16 + fr) * 32 + fq * 8];
#pragma unroll
    for (int m = 0; m < 4; ++m)
#pragma unroll
      for (int n = 0; n < 4; ++n)
        acc[m][n] = __builtin_amdgcn_mfma_f32_16x16x32_bf16(af[m], bfm[n],
                                                            acc[m][n], 0, 0, 0);
    __syncthreads();
  }

  const int orow = m0 + wr * 64 + fq * 4;
  const int ocol = n0 + wc * 64 + fr;
#pragma unroll
  for (int m = 0; m < 4; ++m) {
#pragma unroll
    for (int n = 0; n < 4; ++n) {
      const int cc = ocol + n * 16;
#pragma unroll
      for (int j = 0; j < 4; ++j) {
        const int r = orow + m * 16 + j;
        float v = acc[m][n][j];
        if (EPI == 0) {
          ((float*)Cout)[(size_t)r * N + cc] = v;
        } else if (EPI == 1) {
          ((unsigned short*)Cout)[(size_t)r * N + cc] = f2bf(v);
        } else if (EPI == 2) {
          const size_t idx = (size_t)r * N + cc;
          const float gv = bf2f(aux[idx]);
          ((unsigned short*)Cout)[idx] = f2bf(v * gv * sigmoidf_(gv));
        } else {  // EPI == 3
          if (n0 < 2048)
            ((unsigned short*)Cout)[(size_t)r * 2048 + cc] = f2bf(v);
          else
            ((float*)Cout2)[(size_t)r * 2048 + cc - 2048] = v;
        }
      }
    }
  }
}

// ---------------------------------------------------------------------------
// fp32 -> bf16 flat cast
// ---------------------------------------------------------------------------
__global__ __launch_bounds__(256) void castf2b_kernel(
    const float* __restrict__ in, unsigned short* __restrict__ outp) {
  const size_t i = ((size_t)blockIdx.x * 256 + threadIdx.x) * 8;
  float4 a = *(const float4*)&in[i];
  float4 b = *(const float4*)&in[i + 4];
  u16x8 o;
  o[0] = f2bf(a.x); o[1] = f2bf(a.y); o[2] = f2bf(a.z); o[3] = f2bf(a.w);
  o[4] = f2bf(b.x); o[5] = f2bf(b.y); o[6] = f2bf(b.z); o[7] = f2bf(b.w);
  *(u16x8*)&outp[i] = o;
}

// ---------------------------------------------------------------------------
// fp32 [K][N] -> bf16 [N][K] transpose-cast
// ---------------------------------------------------------------------------
__global__ __launch_bounds__(256) void castT_kernel(
    const float* __restrict__ W, unsigned short* __restrict__ WT, int K, int N) {
  __shared__ float tile[32][33];
  const int n0 = blockIdx.x * 32, k0 = blockIdx.y * 32;
  const int r = threadIdx.x >> 3;
  const int c4 = (threadIdx.x & 7) * 4;
  float4 v = *(const float4*)&W[(size_t)(k0 + r) * N + n0 + c4];
  tile[r][c4 + 0] = v.x; tile[r][c4 + 1] = v.y;
  tile[r][c4 + 2] = v.z; tile[r][c4 + 3] = v.w;
  __syncthreads();
  u16x4 o;
  o[0] = f2bf(tile[c4 + 0][r]); o[1] = f2bf(tile[c4 + 1][r]);
  o[2] = f2bf(tile[c4 + 2][r]); o[3] = f2bf(tile[c4 + 3][r]);
  *(u16x4*)&WT[(size_t)(n0 + r) * K + k0 + c4] = o;
}

// ---------------------------------------------------------------------------
// Gate pre-activations (fp32)
// ---------------------------------------------------------------------------
__global__ __launch_bounds__(256) void gates_kernel(
    const float* __restrict__ x, const float* __restrict__ Wi,
    const float* __restrict__ bi, const float* __restrict__ Wf,
    const float* __restrict__ bf, float* __restrict__ icap,
    float* __restrict__ fls) {
  const int t = blockIdx.x;
  const int tid = threadIdx.x;
  __shared__ float xs[2048];
  *(float4*)&xs[tid * 4] = *(const float4*)&x[(size_t)t * 2048 + tid * 4];
  *(float4*)&xs[1024 + tid * 4] =
      *(const float4*)&x[(size_t)t * 2048 + 1024 + tid * 4];
  __syncthreads();
  const int wave = tid >> 6, lane = tid & 63;
  const int b = t >> 10, s = t & 1023;
  for (int gg = wave; gg < 16; gg += 4) {
    const int head = gg >> 1;
    const int isF = gg & 1;
    const float* W = isF ? Wf : Wi;
    float acc = 0.f;
    for (int d = lane; d < 2048; d += 64) acc = fmaf(xs[d], W[d * 8 + head], acc);
#pragma unroll
    for (int m = 32; m > 0; m >>= 1) acc += __shfl_down(acc, m, 64);
    if (lane == 0) {
      const size_t o = (size_t)(b * 8 + head) * 1024 + s;
      if (isF) fls[o] = logsigf_(softcapf_(acc + bf[head]));
      else icap[o] = softcapf_(acc + bi[head]);
    }
  }
}

// ---------------------------------------------------------------------------
// Per-(b,h) scans: lfc = cumsum(fls); g = icap - lfc; mx = cummax(g)
// ---------------------------------------------------------------------------
__global__ __launch_bounds__(1024) void scan_kernel(
    const float* __restrict__ icap, const float* __restrict__ fls,
    float* __restrict__ lfc, float* __restrict__ garr, float* __restrict__ mx) {
  const int bh = blockIdx.x;
  const int tid = threadIdx.x;
  __shared__ float sm[1024];
  sm[tid] = fls[(size_t)bh * 1024 + tid];
  __syncthreads();
  for (int off = 1; off < 1024; off <<= 1) {
    float v = sm[tid];
    if (tid >= off) v += sm[tid - off];
    __syncthreads();
    sm[tid] = v;
    __syncthreads();
  }
  const float l = sm[tid];
  lfc[(size_t)bh * 1024 + tid] = l;
  const float g = icap[(size_t)bh * 1024 + tid] - l;
  garr[(size_t)bh * 1024 + tid] = g;
  __syncthreads();
  sm[tid] = g;
  __syncthreads();
  for (int off = 1; off < 1024; off <<= 1) {
    float v = sm[tid];
    if (tid >= off) v = fmaxf(v, sm[tid - off]);
    __syncthreads();
    sm[tid] = v;
    __syncthreads();
  }
  mx[(size_t)bh * 1024 + tid] = sm[tid];
}

// ---------------------------------------------------------------------------
// mLSTM core — bf16 MFMA flash-style.
// qkb: bf16 [2048][2048] (q at col h*128, k at 1024+h*128)
// vb : bf16 [2048][2048]
// Swapped QK^T (C[s][t]) -> P in B-frag layout of 16x16x16 mfma; V via
// ds_read_b64_tr_b16 from subtiled LDS. 128 threads (2 waves x 16 t-rows),
// t-block 32, s-block 32.
// ---------------------------------------------------------------------------
__global__ __launch_bounds__(128) void mlstm_mfma_kernel(
    const unsigned short* __restrict__ qkb, const unsigned short* __restrict__ vb,
    const float* __restrict__ garr, const float* __restrict__ lfc,
    const float* __restrict__ mx, float* __restrict__ h) {
  __shared__ unsigned short k_lds[32 * 128];  // [s][d] chunks XOR-swizzled
  __shared__ unsigned short v_lds[32 * 256];  // [W][D][g][j][c] subtiled
  const int tid = threadIdx.x;
  const int lane = tid & 63;
  const int w = tid >> 6;
  const int bh = blockIdx.y;
  const int b = bh >> 3, hh = bh & 7;
  const int tb = blockIdx.x;
  const int fr = lane & 15, fq = lane >> 4;
  const int tw = tb * 32 + w * 16 + fr;  // this lane's t row
  const size_t tokT = (size_t)(b * SEQ + tw);
  const float scale = 0.08838834764831845f;  // 128^-0.5

  // q B-fragments held in registers (n = t = fr, k = d = fq*8+j per kd)
  bf16x8 qf[4];
#pragma unroll
  for (int kd = 0; kd < 4; ++kd)
    qf[kd] = *(const bf16x8*)&qkb[tokT * 2048 + hh * 128 + kd * 32 + fq * 8];

  const float Mt = mx[(size_t)bh * SEQ + tw];
  const float mt = lfc[(size_t)bh * SEQ + tw] + Mt;

  f32x4 acc[16];
  const f32x4 zero = {0.f, 0.f, 0.f, 0.f};
#pragma unroll
  for (int D = 0; D < 16; ++D) acc[D] = zero;
  float asum = 0.f;

  const unsigned vbase = lds_off(v_lds);
  const int nsb = tb + 1;

  for (int sb = 0; sb < nsb; ++sb) {
    const int s0 = sb * 32;
    if (sb) __syncthreads();  // WAR: LDS reuse
    // stage K tile [32][128] bf16, chunk-swizzled: LDS chunk (s,c) holds
    // global chunk (s, c^(s&7))
#pragma unroll
    for (int it = 0; it < 4; ++it) {
      const int ck = it * 128 + tid;
      const int s = ck >> 4, c = ck & 15;
      const int cg = c ^ (s & 7);
      gload16(&qkb[(size_t)(b * SEQ + s0 + s) * 2048 + 1024 + hh * 128 + cg * 8],
              &k_lds[ck * 8]);
    }
    // stage V tile [32 s][256 dv] in tr_read subtile layout
#pragma unroll
    for (int it = 0; it < 8; ++it) {
      const int cv = it * 128 + tid;
      const int W_ = cv >> 9, D = (cv >> 5) & 15, g = (cv >> 3) & 3,
                jj = (cv >> 1) & 3, c2 = cv & 1;
      const int s = W_ * 16 + g * 4 + jj;
      gload16(&vb[(size_t)(b * SEQ + s0 + s) * 2048 + hh * 256 + D * 16 + c2 * 8],
              &v_lds[cv * 8]);
    }
    __syncthreads();

#pragma unroll
    for (int st = 0; st < 2; ++st) {
      // QK^T swapped: C[s][t], A = K rows (m=s), B = q regs (n=t)
      f32x4 cfrag = zero;
      const int srow = st * 16 + fr;
#pragma unroll
      for (int kd = 0; kd < 4; ++kd) {
        const int cc = (kd * 4 + fq) ^ (srow & 7);
        const bf16x8 kf = *(const bf16x8*)&k_lds[srow * 128 + cc * 8];
        cfrag = __builtin_amdgcn_mfma_f32_16x16x32_bf16(kf, qf[kd], cfrag, 0, 0, 0);
      }
      // weights: w = score*scale*exp(g[s]-Mt), causal mask
      const int sbase = s0 + st * 16 + fq * 4;
      const float4 g4 = *(const float4*)&garr[(size_t)bh * SEQ + sbase];
      float wv[4];
      wv[0] = (sbase + 0 <= tw) ? cfrag[0] * scale * __expf(g4.x - Mt) : 0.f;
      wv[1] = (sbase + 1 <= tw) ? cfrag[1] * scale * __expf(g4.y - Mt) : 0.f;
      wv[2] = (sbase + 2 <= tw) ? cfrag[2] * scale * __expf(g4.z - Mt) : 0.f;
      wv[3] = (sbase + 3 <= tw) ? cfrag[3] * scale * __expf(g4.w - Mt) : 0.f;
      asum += wv[0] + wv[1] + wv[2] + wv[3];
      bf16x4 pf;
      pf[0] = (short)f2bf(wv[0]); pf[1] = (short)f2bf(wv[1]);
      pf[2] = (short)f2bf(wv[2]); pf[3] = (short)f2bf(wv[3]);

      // PV: A = v^T via tr_read (m=dv, k=s), B = pf (n=t, k=s)
#pragma unroll
      for (int Dg = 0; Dg < 2; ++Dg) {
        bf16x4 vf[8];
#pragma unroll
        for (int D = 0; D < 8; ++D)
          vf[D] = tr_read(vbase + (st * 4096 + (Dg * 8 + D) * 256) * 2 + lane * 8);
        asm volatile("s_waitcnt lgkmcnt(0)" ::: "memory");
        __builtin_amdgcn_sched_barrier(0);
#pragma unroll
        for (int D = 0; D < 8; ++D)
          acc[Dg * 8 + D] = mfma16_bf16(vf[D], pf, acc[Dg * 8 + D]);
      }
    }
  }

  // row-sum reduce across the 4 fq groups (same t = lane&15)
  asum += __shfl_xor(asum, 16, 64);
  asum += __shfl_xor(asum, 32, 64);
  const float n = fmaxf(fabsf(asum), __expf(-mt));
  const float inv = 1.f / (n + 1e-6f);
  asm volatile("s_nop 7\n\ts_nop 7" ::);  // MFMA->VALU guard (asm-mfma path)
  float* hrow = &h[tokT * 2048 + hh * 256];
#pragma unroll
  for (int D = 0; D < 16; ++D) {
    float4 o4;
    o4.x = acc[D][0] * inv;
    o4.y = acc[D][1] * inv;
    o4.z = acc[D][2] * inv;
    o4.w = acc[D][3] * inv;
    *(float4*)&hrow[D * 16 + fq * 4] = o4;
  }
}

// ---------------------------------------------------------------------------
// Multi-head RMS * mh_norm_w, gated by sigmoid(o_preact) -> bf16
// ---------------------------------------------------------------------------
__global__ __launch_bounds__(256) void hout_kernel(
    const float* __restrict__ h, const float* __restrict__ obuf,
    const float* __restrict__ mhw, unsigned short* __restrict__ houtb) {
  const int t = blockIdx.x;
  const int tid = threadIdx.x;
  const size_t base = (size_t)t * 2048 + tid * 8;
  float vals[8];
  *(float4*)&vals[0] = *(const float4*)&h[base];
  *(float4*)&vals[4] = *(const float4*)&h[base + 4];
  float ss = 0.f;
#pragma unroll
  for (int j = 0; j < 8; ++j) ss += vals[j] * vals[j];
#pragma unroll
  for (int m = 16; m > 0; m >>= 1) ss += __shfl_xor(ss, m, 32);
  const float rinv = rsqrtf(ss * (1.f / 256.f) + 1e-6f);
  float ov[8];
  *(float4*)&ov[0] = *(const float4*)&obuf[base];
  *(float4*)&ov[4] = *(const float4*)&obuf[base + 4];
  u16x8 res;
#pragma unroll
  for (int j = 0; j < 8; ++j) {
    const float hn = vals[j] * rinv * mhw[tid * 8 + j];
    res[j] = f2bf(hn * sigmoidf_(ov[j]));
  }
  *(u16x8*)&houtb[base] = res;
}

// ---------------------------------------------------------------------------
// out = base + w * y * rsqrt(mean(y^2)+eps); optional bf16 copy
// ---------------------------------------------------------------------------
template <int EMIT_BF16>
__global__ __launch_bounds__(256) void addrms_kernel(
    const float* __restrict__ base_, const float* __restrict__ y,
    const float* __restrict__ w, float* __restrict__ outp,
    unsigned short* __restrict__ outb) {
  const int t = blockIdx.x;
  const int tid = threadIdx.x;
  __shared__ float red[4];
  const size_t boff = (size_t)t * 2048 + tid * 8;
  float vals[8];
  *(float4*)&vals[0] = *(const float4*)&y[boff];
  *(float4*)&vals[4] = *(const float4*)&y[boff + 4];
  float ss = 0.f;
#pragma unroll
  for (int j = 0; j < 8; ++j) ss += vals[j] * vals[j];
#pragma unroll
  for (int m = 32; m > 0; m >>= 1) ss += __shfl_xor(ss, m, 64);
  if ((tid & 63) == 0) red[tid >> 6] = ss;
  __syncthreads();
  ss = red[0] + red[1] + red[2] + red[3];
  const float rinv = rsqrtf(ss * (1.f / 2048.f) + 1e-6f);
  float bv[8];
  *(float4*)&bv[0] = *(const float4*)&base_[boff];
  *(float4*)&bv[4] = *(const float4*)&base_[boff + 4];
  float res[8];
  u16x8 rb;
#pragma unroll
  for (int j = 0; j < 8; ++j) {
    res[j] = bv[j] + vals[j] * rinv * w[tid * 8 + j];
    if (EMIT_BF16) rb[j] = f2bf(res[j]);
  }
  *(float4*)&outp[boff] = *(float4*)&res[0];
  *(float4*)&outp[boff + 4] = *(float4*)&res[4];
  if (EMIT_BF16) *(u16x8*)&outb[boff] = rb;
}

// ---------------------------------------------------------------------------
extern "C" void kernel_launch(void* const* d_in, const int* in_sizes, int n_in,
                              void* d_out, int out_size, void* d_ws,
                              size_t ws_size, hipStream_t stream) {
  const float* x = (const float*)d_in[0];
  const float* Wq = (const float*)d_in[1];
  const float* Wk = (const float*)d_in[2];
  const float* Wv = (const float*)d_in[3];
  const float* Wo = (const float*)d_in[4];
  const float* Wi = (const float*)d_in[5];
  const float* bi = (const float*)d_in[6];
  const float* Wf = (const float*)d_in[7];
  const float* bf = (const float*)d_in[8];
  const float* mhw = (const float*)d_in[9];
  const float* Wout = (const float*)d_in[10];
  const float* rms1 = (const float*)d_in[11];
  const float* Wgate = (const float*)d_in[12];
  const float* Wup = (const float*)d_in[13];
  const float* Wdown = (const float*)d_in[14];
  const float* rms2 = (const float*)d_in[15];
  float* out = (float*)d_out;
  char* base = (char*)d_ws;
  const size_t MBy = 1024 * 1024;

  // Workspace (byte offsets, MB), single-stream lifetime reuse:
  //   0.. 32 W      (bf16 transposed weights, reused per GEMM)
  //  32.. 40 xb     bf16 x
  //  40.. 48 qkb    bf16 q|k     -> f1 fp32 (40..56) after mlstm
  //  48.. 56 vb     bf16 v
  //  56.. 72 obuf   fp32 o       -> gbuf bf16 (56..88) after hout
  //  72.. 88 h      fp32
  //  88.. 96 houtb  bf16         -> actb bf16 (88..120) after attn/addrms
  //  96..112 attn   fp32
  // 120..128 f1b    bf16
  //  56.. 72 mlp    fp32 (after up-GEMM consumed gbuf)
  // 128..    gate scalars
  unsigned short* W = (unsigned short*)(base);
  unsigned short* xb = (unsigned short*)(base + 32 * MBy);
  unsigned short* qkb = (unsigned short*)(base + 40 * MBy);
  unsigned short* vb = (unsigned short*)(base + 48 * MBy);
  float* obuf = (float*)(base + 56 * MBy);
  float* h = (float*)(base + 72 * MBy);
  unsigned short* houtb = (unsigned short*)(base + 88 * MBy);
  float* attn = (float*)(base + 96 * MBy);
  float* f1 = (float*)(base + 40 * MBy);
  unsigned short* f1b = (unsigned short*)(base + 120 * MBy);
  unsigned short* gbuf = (unsigned short*)(base + 56 * MBy);
  unsigned short* actb = (unsigned short*)(base + 88 * MBy);
  float* mlp = (float*)(base + 56 * MBy);
  float* gs = (float*)(base + 128 * MBy);
  float* icap = gs;
  float* fls = gs + 16384;
  float* lfc = gs + 32768;
  float* garr = gs + 49152;
  float* mxp = gs + 65536;

  const dim3 blk(256);

  castf2b_kernel<<<TOKENS, blk, 0, stream>>>(x, xb);
  gates_kernel<<<TOKENS, blk, 0, stream>>>(x, Wi, bi, Wf, bf, icap, fls);
  scan_kernel<<<16, 1024, 0, stream>>>(icap, fls, lfc, garr, mxp);

  // qkb = xb @ [Wq|Wk]  (bf16 out)
  castT_kernel<<<dim3(32, 64), blk, 0, stream>>>(Wq, W, 2048, 1024);
  castT_kernel<<<dim3(32, 64), blk, 0, stream>>>(Wk, W + 1024 * 2048, 2048, 1024);
  gemm_bf16<1><<<dim3(16, 16), blk, 0, stream>>>(xb, W, qkb, nullptr, nullptr,
                                                 TOKENS, 2048, 2048);

  // [vb bf16 | obuf fp32] = xb @ [Wv|Wo]
  castT_kernel<<<dim3(64, 64), blk, 0, stream>>>(Wv, W, 2048, 2048);
  castT_kernel<<<dim3(64, 64), blk, 0, stream>>>(Wo, W + 2048 * 2048, 2048, 2048);
  gemm_bf16<3><<<dim3(32, 16), blk, 0, stream>>>(xb, W, vb, obuf, nullptr,
                                                 TOKENS, 4096, 2048);

  // mLSTM core (MFMA) + multi-head norm + output gate
  mlstm_mfma_kernel<<<dim3(32, 16), dim3(128), 0, stream>>>(qkb, vb, garr, lfc,
                                                            mxp, h);
  hout_kernel<<<TOKENS, blk, 0, stream>>>(h, obuf, mhw, houtb);

  // attn = houtb @ Wout (fp32 out)
  castT_kernel<<<dim3(64, 64), blk, 0, stream>>>(Wout, W, 2048, 2048);
  gemm_bf16<0><<<dim3(16, 16), blk, 0, stream>>>(houtb, W, attn, nullptr,
                                                 nullptr, TOKENS, 2048, 2048);

  // f1 = x + rms(attn); f1b bf16
  addrms_kernel<1><<<TOKENS, blk, 0, stream>>>(x, attn, rms1, f1, f1b);

  // MLP
  castT_kernel<<<dim3(256, 64), blk, 0, stream>>>(Wgate, W, 2048, 8192);
  gemm_bf16<1><<<dim3(64, 16), blk, 0, stream>>>(f1b, W, gbuf, nullptr, nullptr,
                                                 TOKENS, 8192, 2048);
  castT_kernel<<<dim3(256, 64), blk, 0, stream>>>(Wup, W, 2048, 8192);
  gemm_bf16<2><<<dim3(64, 16), blk, 0, stream>>>(f1b, W, actb, nullptr, gbuf,
                                                 TOKENS, 8192, 2048);
  castT_kernel<<<dim3(64, 256), blk, 0, stream>>>(Wdown, W, 8192, 2048);
  gemm_bf16<0><<<dim3(16, 16), blk, 0, stream>>>(actb, W, mlp, nullptr, nullptr,
                                                 TOKENS, 2048, 8192);

  // out = f1 + rms(mlp)
  addrms_kernel<0><<<TOKENS, blk, 0, stream>>>(f1, mlp, rms2, out, nullptr);
}

// Round 4
// 779.522 us; speedup vs baseline: 6.7428x; 1.0732x over previous
//
#include <hip/hip_runtime.h>
#include <hip/hip_bf16.h>

// B=2, S=1024, D=2048, NH=8, dqk=128, dv=256, I=8192
#define TOKENS 2048
#define DMODEL 2048
#define SEQ    1024

typedef __attribute__((ext_vector_type(8))) short bf16x8;
typedef __attribute__((ext_vector_type(4))) short bf16x4;
typedef __attribute__((ext_vector_type(4))) float f32x4;
typedef __attribute__((ext_vector_type(8))) unsigned short u16x8;
typedef __attribute__((ext_vector_type(4))) unsigned short u16x4;

__device__ __forceinline__ float sigmoidf_(float x) { return 1.f / (1.f + expf(-x)); }
__device__ __forceinline__ float softcapf_(float x) { return 15.f * tanhf(x * (1.f / 15.f)); }
__device__ __forceinline__ float logsigf_(float x) {
  return (x >= 0.f) ? -log1pf(expf(-x)) : (x - log1pf(expf(x)));
}
__device__ __forceinline__ unsigned short f2bf(float f) {  // RNE, inputs finite
  unsigned u = __builtin_bit_cast(unsigned, f);
  u += 0x7FFFu + ((u >> 16) & 1u);
  return (unsigned short)(u >> 16);
}
__device__ __forceinline__ float bf2f(unsigned short b) {
  unsigned u = ((unsigned)b) << 16;
  return __builtin_bit_cast(float, u);
}

typedef __attribute__((address_space(3))) void lds_void;
typedef const __attribute__((address_space(1))) void gmem_void;
__device__ __forceinline__ void gload16(const void* g, void* l) {
  __builtin_amdgcn_global_load_lds((gmem_void*)g, (lds_void*)l, 16, 0, 0);
}
__device__ __forceinline__ unsigned lds_off(const void* p) {
  return (unsigned)(size_t)(__attribute__((address_space(3))) const void*)p;
}

#if defined(__has_builtin)
#if __has_builtin(__builtin_amdgcn_mfma_f32_16x16x16bf16_1k)
#define HAVE_MFMA16 1
#endif
#endif

__device__ __forceinline__ f32x4 mfma16_bf16(bf16x4 a, bf16x4 b, f32x4 c) {
#ifdef HAVE_MFMA16
  return __builtin_amdgcn_mfma_f32_16x16x16bf16_1k(a, b, c, 0, 0, 0);
#else
  f32x4 d;
  asm volatile("v_mfma_f32_16x16x16_bf16 %0, %1, %2, %3"
               : "=v"(d) : "v"(a), "v"(b), "v"(c));
  return d;
#endif
}

__device__ __forceinline__ bf16x4 tr_read(unsigned addr) {
  bf16x4 d;
  asm volatile("ds_read_b64_tr_b16 %0, %1" : "=v"(d) : "v"(addr));
  return d;
}

// ---------------------------------------------------------------------------
// bf16 MFMA GEMM, 2-phase double-buffered (T3 minimum recipe):
// C[M,N] = A[M,K] @ BT[N,K]^T. 128x128 tile, BK=32, 256 threads = 4 waves,
// 4x4 16x16x32 fragments. Per iter: STAGE(next)->buf^1, ds_read+MFMA on buf,
// one __syncthreads (vmcnt+lgkm drain lands after a tile of compute).
// EPI 0: fp32 out. EPI 1: bf16 out. EPI 2: bf16 out = silu(aux)*acc.
// EPI 3: split — cols <2048 bf16 -> Cout; cols >=2048 fp32 -> Cout2.
// ---------------------------------------------------------------------------
template <int EPI>
__global__ __launch_bounds__(256) void gemm_bf16(
    const unsigned short* __restrict__ A, const unsigned short* __restrict__ BT,
    void* __restrict__ Cout, void* __restrict__ Cout2,
    const unsigned short* __restrict__ aux, int M, int N, int K) {
  __shared__ unsigned short As[2][128 * 32];
  __shared__ unsigned short Bs[2][128 * 32];
  const int tid = threadIdx.x;
  const int m0 = blockIdx.y * 128;
  const int n0 = blockIdx.x * 128;
  const int wid = tid >> 6;
  const int lane = tid & 63;
  const int wr = wid >> 1, wc = wid & 1;
  const int fr = lane & 15, fq = lane >> 4;

  const f32x4 zero = {0.f, 0.f, 0.f, 0.f};
  f32x4 acc[4][4];
#pragma unroll
  for (int m = 0; m < 4; ++m)
#pragma unroll
    for (int n = 0; n < 4; ++n) acc[m][n] = zero;

  const int srow = tid >> 2;
  const int scol = (tid & 3) * 8;
  const unsigned short* Ag0 = A + (size_t)(m0 + srow) * K + scol;
  const unsigned short* Ag1 = A + (size_t)(m0 + 64 + srow) * K + scol;
  const unsigned short* Bg0 = BT + (size_t)(n0 + srow) * K + scol;
  const unsigned short* Bg1 = BT + (size_t)(n0 + 64 + srow) * K + scol;

  // prologue: stage K-tile 0 into buf 0
  gload16(Ag0, &As[0][tid * 8]);
  gload16(Ag1, &As[0][2048 + tid * 8]);
  gload16(Bg0, &Bs[0][tid * 8]);
  gload16(Bg1, &Bs[0][2048 + tid * 8]);
  __syncthreads();

  const int nt = K >> 5;
  for (int t = 0; t < nt; ++t) {
    const int cur = t & 1;
    if (t + 1 < nt) {  // issue next-tile stage FIRST (overlaps with compute)
      const int k0 = (t + 1) << 5;
      gload16(Ag0 + k0, &As[cur ^ 1][tid * 8]);
      gload16(Ag1 + k0, &As[cur ^ 1][2048 + tid * 8]);
      gload16(Bg0 + k0, &Bs[cur ^ 1][tid * 8]);
      gload16(Bg1 + k0, &Bs[cur ^ 1][2048 + tid * 8]);
    }
    bf16x8 af[4], bfm[4];
#pragma unroll
    for (int m = 0; m < 4; ++m)
      af[m] = *(const bf16x8*)&As[cur][(wr * 64 + m * 16 + fr) * 32 + fq * 8];
#pragma unroll
    for (int n = 0; n < 4; ++n)
      bfm[n] = *(const bf16x8*)&Bs[cur][(wc * 64 + n * 16 + fr) * 32 + fq * 8];
#pragma unroll
    for (int m = 0; m < 4; ++m)
#pragma unroll
      for (int n = 0; n < 4; ++n)
        acc[m][n] = __builtin_amdgcn_mfma_f32_16x16x32_bf16(af[m], bfm[n],
                                                            acc[m][n], 0, 0, 0);
    __syncthreads();  // vmcnt(0)+lgkmcnt(0)+barrier: next buf ready, cur free
  }

  const int orow = m0 + wr * 64 + fq * 4;
  const int ocol = n0 + wc * 64 + fr;
#pragma unroll
  for (int m = 0; m < 4; ++m) {
#pragma unroll
    for (int n = 0; n < 4; ++n) {
      const int cc = ocol + n * 16;
#pragma unroll
      for (int j = 0; j < 4; ++j) {
        const int r = orow + m * 16 + j;
        float v = acc[m][n][j];
        if (EPI == 0) {
          ((float*)Cout)[(size_t)r * N + cc] = v;
        } else if (EPI == 1) {
          ((unsigned short*)Cout)[(size_t)r * N + cc] = f2bf(v);
        } else if (EPI == 2) {
          const size_t idx = (size_t)r * N + cc;
          const float gv = bf2f(aux[idx]);
          ((unsigned short*)Cout)[idx] = f2bf(v * gv * sigmoidf_(gv));
        } else {  // EPI == 3
          if (n0 < 2048)
            ((unsigned short*)Cout)[(size_t)r * 2048 + cc] = f2bf(v);
          else
            ((float*)Cout2)[(size_t)r * 2048 + cc - 2048] = v;
        }
      }
    }
  }
}

// ---------------------------------------------------------------------------
// fp32 -> bf16 flat cast
// ---------------------------------------------------------------------------
__global__ __launch_bounds__(256) void castf2b_kernel(
    const float* __restrict__ in, unsigned short* __restrict__ outp) {
  const size_t i = ((size_t)blockIdx.x * 256 + threadIdx.x) * 8;
  float4 a = *(const float4*)&in[i];
  float4 b = *(const float4*)&in[i + 4];
  u16x8 o;
  o[0] = f2bf(a.x); o[1] = f2bf(a.y); o[2] = f2bf(a.z); o[3] = f2bf(a.w);
  o[4] = f2bf(b.x); o[5] = f2bf(b.y); o[6] = f2bf(b.z); o[7] = f2bf(b.w);
  *(u16x8*)&outp[i] = o;
}

// ---------------------------------------------------------------------------
// fp32 [K][N] -> bf16 [N][K] transpose-cast
// ---------------------------------------------------------------------------
__global__ __launch_bounds__(256) void castT_kernel(
    const float* __restrict__ W, unsigned short* __restrict__ WT, int K, int N) {
  __shared__ float tile[32][33];
  const int n0 = blockIdx.x * 32, k0 = blockIdx.y * 32;
  const int r = threadIdx.x >> 3;
  const int c4 = (threadIdx.x & 7) * 4;
  float4 v = *(const float4*)&W[(size_t)(k0 + r) * N + n0 + c4];
  tile[r][c4 + 0] = v.x; tile[r][c4 + 1] = v.y;
  tile[r][c4 + 2] = v.z; tile[r][c4 + 3] = v.w;
  __syncthreads();
  u16x4 o;
  o[0] = f2bf(tile[c4 + 0][r]); o[1] = f2bf(tile[c4 + 1][r]);
  o[2] = f2bf(tile[c4 + 2][r]); o[3] = f2bf(tile[c4 + 3][r]);
  *(u16x4*)&WT[(size_t)(n0 + r) * K + k0 + c4] = o;
}

// ---------------------------------------------------------------------------
// Gate pre-activations (fp32)
// ---------------------------------------------------------------------------
__global__ __launch_bounds__(256) void gates_kernel(
    const float* __restrict__ x, const float* __restrict__ Wi,
    const float* __restrict__ bi, const float* __restrict__ Wf,
    const float* __restrict__ bf, float* __restrict__ icap,
    float* __restrict__ fls) {
  const int t = blockIdx.x;
  const int tid = threadIdx.x;
  __shared__ float xs[2048];
  *(float4*)&xs[tid * 4] = *(const float4*)&x[(size_t)t * 2048 + tid * 4];
  *(float4*)&xs[1024 + tid * 4] =
      *(const float4*)&x[(size_t)t * 2048 + 1024 + tid * 4];
  __syncthreads();
  const int wave = tid >> 6, lane = tid & 63;
  const int b = t >> 10, s = t & 1023;
  for (int gg = wave; gg < 16; gg += 4) {
    const int head = gg >> 1;
    const int isF = gg & 1;
    const float* W = isF ? Wf : Wi;
    float acc = 0.f;
    for (int d = lane; d < 2048; d += 64) acc = fmaf(xs[d], W[d * 8 + head], acc);
#pragma unroll
    for (int m = 32; m > 0; m >>= 1) acc += __shfl_down(acc, m, 64);
    if (lane == 0) {
      const size_t o = (size_t)(b * 8 + head) * 1024 + s;
      if (isF) fls[o] = logsigf_(softcapf_(acc + bf[head]));
      else icap[o] = softcapf_(acc + bi[head]);
    }
  }
}

// ---------------------------------------------------------------------------
// Per-(b,h) scans: lfc = cumsum(fls); g = icap - lfc; mx = cummax(g)
// ---------------------------------------------------------------------------
__global__ __launch_bounds__(1024) void scan_kernel(
    const float* __restrict__ icap, const float* __restrict__ fls,
    float* __restrict__ lfc, float* __restrict__ garr, float* __restrict__ mx) {
  const int bh = blockIdx.x;
  const int tid = threadIdx.x;
  __shared__ float sm[1024];
  sm[tid] = fls[(size_t)bh * 1024 + tid];
  __syncthreads();
  for (int off = 1; off < 1024; off <<= 1) {
    float v = sm[tid];
    if (tid >= off) v += sm[tid - off];
    __syncthreads();
    sm[tid] = v;
    __syncthreads();
  }
  const float l = sm[tid];
  lfc[(size_t)bh * 1024 + tid] = l;
  const float g = icap[(size_t)bh * 1024 + tid] - l;
  garr[(size_t)bh * 1024 + tid] = g;
  __syncthreads();
  sm[tid] = g;
  __syncthreads();
  for (int off = 1; off < 1024; off <<= 1) {
    float v = sm[tid];
    if (tid >= off) v = fmaxf(v, sm[tid - off]);
    __syncthreads();
    sm[tid] = v;
    __syncthreads();
  }
  mx[(size_t)bh * 1024 + tid] = sm[tid];
}

// ---------------------------------------------------------------------------
// mLSTM core — bf16 MFMA flash-style (swapped QK^T, tr_read V).
// ---------------------------------------------------------------------------
__global__ __launch_bounds__(128) void mlstm_mfma_kernel(
    const unsigned short* __restrict__ qkb, const unsigned short* __restrict__ vb,
    const float* __restrict__ garr, const float* __restrict__ lfc,
    const float* __restrict__ mx, float* __restrict__ h) {
  __shared__ unsigned short k_lds[32 * 128];  // [s][d] chunks XOR-swizzled
  __shared__ unsigned short v_lds[32 * 256];  // [W][D][g][j][c] subtiled
  const int tid = threadIdx.x;
  const int lane = tid & 63;
  const int w = tid >> 6;
  const int bh = blockIdx.y;
  const int b = bh >> 3, hh = bh & 7;
  const int tb = blockIdx.x;
  const int fr = lane & 15, fq = lane >> 4;
  const int tw = tb * 32 + w * 16 + fr;
  const size_t tokT = (size_t)(b * SEQ + tw);
  const float scale = 0.08838834764831845f;  // 128^-0.5

  bf16x8 qf[4];
#pragma unroll
  for (int kd = 0; kd < 4; ++kd)
    qf[kd] = *(const bf16x8*)&qkb[tokT * 2048 + hh * 128 + kd * 32 + fq * 8];

  const float Mt = mx[(size_t)bh * SEQ + tw];
  const float mt = lfc[(size_t)bh * SEQ + tw] + Mt;

  f32x4 acc[16];
  const f32x4 zero = {0.f, 0.f, 0.f, 0.f};
#pragma unroll
  for (int D = 0; D < 16; ++D) acc[D] = zero;
  float asum = 0.f;

  const unsigned vbase = lds_off(v_lds);
  const int nsb = tb + 1;

  for (int sb = 0; sb < nsb; ++sb) {
    const int s0 = sb * 32;
    if (sb) __syncthreads();
#pragma unroll
    for (int it = 0; it < 4; ++it) {
      const int ck = it * 128 + tid;
      const int s = ck >> 4, c = ck & 15;
      const int cg = c ^ (s & 7);
      gload16(&qkb[(size_t)(b * SEQ + s0 + s) * 2048 + 1024 + hh * 128 + cg * 8],
              &k_lds[ck * 8]);
    }
#pragma unroll
    for (int it = 0; it < 8; ++it) {
      const int cv = it * 128 + tid;
      const int W_ = cv >> 9, D = (cv >> 5) & 15, g = (cv >> 3) & 3,
                jj = (cv >> 1) & 3, c2 = cv & 1;
      const int s = W_ * 16 + g * 4 + jj;
      gload16(&vb[(size_t)(b * SEQ + s0 + s) * 2048 + hh * 256 + D * 16 + c2 * 8],
              &v_lds[cv * 8]);
    }
    __syncthreads();

#pragma unroll
    for (int st = 0; st < 2; ++st) {
      f32x4 cfrag = zero;
      const int srow = st * 16 + fr;
#pragma unroll
      for (int kd = 0; kd < 4; ++kd) {
        const int cc = (kd * 4 + fq) ^ (srow & 7);
        const bf16x8 kf = *(const bf16x8*)&k_lds[srow * 128 + cc * 8];
        cfrag = __builtin_amdgcn_mfma_f32_16x16x32_bf16(kf, qf[kd], cfrag, 0, 0, 0);
      }
      const int sbase = s0 + st * 16 + fq * 4;
      const float4 g4 = *(const float4*)&garr[(size_t)bh * SEQ + sbase];
      float wv[4];
      wv[0] = (sbase + 0 <= tw) ? cfrag[0] * scale * __expf(g4.x - Mt) : 0.f;
      wv[1] = (sbase + 1 <= tw) ? cfrag[1] * scale * __expf(g4.y - Mt) : 0.f;
      wv[2] = (sbase + 2 <= tw) ? cfrag[2] * scale * __expf(g4.z - Mt) : 0.f;
      wv[3] = (sbase + 3 <= tw) ? cfrag[3] * scale * __expf(g4.w - Mt) : 0.f;
      asum += wv[0] + wv[1] + wv[2] + wv[3];
      bf16x4 pf;
      pf[0] = (short)f2bf(wv[0]); pf[1] = (short)f2bf(wv[1]);
      pf[2] = (short)f2bf(wv[2]); pf[3] = (short)f2bf(wv[3]);

#pragma unroll
      for (int Dg = 0; Dg < 2; ++Dg) {
        bf16x4 vf[8];
#pragma unroll
        for (int D = 0; D < 8; ++D)
          vf[D] = tr_read(vbase + (st * 4096 + (Dg * 8 + D) * 256) * 2 + lane * 8);
        asm volatile("s_waitcnt lgkmcnt(0)" ::: "memory");
        __builtin_amdgcn_sched_barrier(0);
#pragma unroll
        for (int D = 0; D < 8; ++D)
          acc[Dg * 8 + D] = mfma16_bf16(vf[D], pf, acc[Dg * 8 + D]);
      }
    }
  }

  asum += __shfl_xor(asum, 16, 64);
  asum += __shfl_xor(asum, 32, 64);
  const float n = fmaxf(fabsf(asum), __expf(-mt));
  const float inv = 1.f / (n + 1e-6f);
  asm volatile("s_nop 7\n\ts_nop 7" ::);  // MFMA->VALU guard (asm-mfma path)
  float* hrow = &h[tokT * 2048 + hh * 256];
#pragma unroll
  for (int D = 0; D < 16; ++D) {
    float4 o4;
    o4.x = acc[D][0] * inv;
    o4.y = acc[D][1] * inv;
    o4.z = acc[D][2] * inv;
    o4.w = acc[D][3] * inv;
    *(float4*)&hrow[D * 16 + fq * 4] = o4;
  }
}

// ---------------------------------------------------------------------------
// Multi-head RMS * mh_norm_w, gated by sigmoid(o_preact) -> bf16
// ---------------------------------------------------------------------------
__global__ __launch_bounds__(256) void hout_kernel(
    const float* __restrict__ h, const float* __restrict__ obuf,
    const float* __restrict__ mhw, unsigned short* __restrict__ houtb) {
  const int t = blockIdx.x;
  const int tid = threadIdx.x;
  const size_t base = (size_t)t * 2048 + tid * 8;
  float vals[8];
  *(float4*)&vals[0] = *(const float4*)&h[base];
  *(float4*)&vals[4] = *(const float4*)&h[base + 4];
  float ss = 0.f;
#pragma unroll
  for (int j = 0; j < 8; ++j) ss += vals[j] * vals[j];
#pragma unroll
  for (int m = 16; m > 0; m >>= 1) ss += __shfl_xor(ss, m, 32);
  const float rinv = rsqrtf(ss * (1.f / 256.f) + 1e-6f);
  float ov[8];
  *(float4*)&ov[0] = *(const float4*)&obuf[base];
  *(float4*)&ov[4] = *(const float4*)&obuf[base + 4];
  u16x8 res;
#pragma unroll
  for (int j = 0; j < 8; ++j) {
    const float hn = vals[j] * rinv * mhw[tid * 8 + j];
    res[j] = f2bf(hn * sigmoidf_(ov[j]));
  }
  *(u16x8*)&houtb[base] = res;
}

// ---------------------------------------------------------------------------
// out = base + w * y * rsqrt(mean(y^2)+eps); optional bf16 copy
// ---------------------------------------------------------------------------
template <int EMIT_BF16>
__global__ __launch_bounds__(256) void addrms_kernel(
    const float* __restrict__ base_, const float* __restrict__ y,
    const float* __restrict__ w, float* __restrict__ outp,
    unsigned short* __restrict__ outb) {
  const int t = blockIdx.x;
  const int tid = threadIdx.x;
  __shared__ float red[4];
  const size_t boff = (size_t)t * 2048 + tid * 8;
  float vals[8];
  *(float4*)&vals[0] = *(const float4*)&y[boff];
  *(float4*)&vals[4] = *(const float4*)&y[boff + 4];
  float ss = 0.f;
#pragma unroll
  for (int j = 0; j < 8; ++j) ss += vals[j] * vals[j];
#pragma unroll
  for (int m = 32; m > 0; m >>= 1) ss += __shfl_xor(ss, m, 64);
  if ((tid & 63) == 0) red[tid >> 6] = ss;
  __syncthreads();
  ss = red[0] + red[1] + red[2] + red[3];
  const float rinv = rsqrtf(ss * (1.f / 2048.f) + 1e-6f);
  float bv[8];
  *(float4*)&bv[0] = *(const float4*)&base_[boff];
  *(float4*)&bv[4] = *(const float4*)&base_[boff + 4];
  float res[8];
  u16x8 rb;
#pragma unroll
  for (int j = 0; j < 8; ++j) {
    res[j] = bv[j] + vals[j] * rinv * w[tid * 8 + j];
    if (EMIT_BF16) rb[j] = f2bf(res[j]);
  }
  *(float4*)&outp[boff] = *(float4*)&res[0];
  *(float4*)&outp[boff + 4] = *(float4*)&res[4];
  if (EMIT_BF16) *(u16x8*)&outb[boff] = rb;
}

// ---------------------------------------------------------------------------
extern "C" void kernel_launch(void* const* d_in, const int* in_sizes, int n_in,
                              void* d_out, int out_size, void* d_ws,
                              size_t ws_size, hipStream_t stream) {
  const float* x = (const float*)d_in[0];
  const float* Wq = (const float*)d_in[1];
  const float* Wk = (const float*)d_in[2];
  const float* Wv = (const float*)d_in[3];
  const float* Wo = (const float*)d_in[4];
  const float* Wi = (const float*)d_in[5];
  const float* bi = (const float*)d_in[6];
  const float* Wf = (const float*)d_in[7];
  const float* bf = (const float*)d_in[8];
  const float* mhw = (const float*)d_in[9];
  const float* Wout = (const float*)d_in[10];
  const float* rms1 = (const float*)d_in[11];
  const float* Wgate = (const float*)d_in[12];
  const float* Wup = (const float*)d_in[13];
  const float* Wdown = (const float*)d_in[14];
  const float* rms2 = (const float*)d_in[15];
  float* out = (float*)d_out;
  char* base = (char*)d_ws;
  const size_t MBy = 1024 * 1024;

  unsigned short* W = (unsigned short*)(base);
  unsigned short* xb = (unsigned short*)(base + 32 * MBy);
  unsigned short* qkb = (unsigned short*)(base + 40 * MBy);
  unsigned short* vb = (unsigned short*)(base + 48 * MBy);
  float* obuf = (float*)(base + 56 * MBy);
  float* h = (float*)(base + 72 * MBy);
  unsigned short* houtb = (unsigned short*)(base + 88 * MBy);
  float* attn = (float*)(base + 96 * MBy);
  float* f1 = (float*)(base + 40 * MBy);
  unsigned short* f1b = (unsigned short*)(base + 120 * MBy);
  unsigned short* gbuf = (unsigned short*)(base + 56 * MBy);
  unsigned short* actb = (unsigned short*)(base + 88 * MBy);
  float* mlp = (float*)(base + 56 * MBy);
  float* gs = (float*)(base + 128 * MBy);
  float* icap = gs;
  float* fls = gs + 16384;
  float* lfc = gs + 32768;
  float* garr = gs + 49152;
  float* mxp = gs + 65536;

  const dim3 blk(256);

  castf2b_kernel<<<TOKENS, blk, 0, stream>>>(x, xb);
  gates_kernel<<<TOKENS, blk, 0, stream>>>(x, Wi, bi, Wf, bf, icap, fls);
  scan_kernel<<<16, 1024, 0, stream>>>(icap, fls, lfc, garr, mxp);

  // qkb = xb @ [Wq|Wk]  (bf16 out)
  castT_kernel<<<dim3(32, 64), blk, 0, stream>>>(Wq, W, 2048, 1024);
  castT_kernel<<<dim3(32, 64), blk, 0, stream>>>(Wk, W + 1024 * 2048, 2048, 1024);
  gemm_bf16<1><<<dim3(16, 16), blk, 0, stream>>>(xb, W, qkb, nullptr, nullptr,
                                                 TOKENS, 2048, 2048);

  // [vb bf16 | obuf fp32] = xb @ [Wv|Wo]
  castT_kernel<<<dim3(64, 64), blk, 0, stream>>>(Wv, W, 2048, 2048);
  castT_kernel<<<dim3(64, 64), blk, 0, stream>>>(Wo, W + 2048 * 2048, 2048, 2048);
  gemm_bf16<3><<<dim3(32, 16), blk, 0, stream>>>(xb, W, vb, obuf, nullptr,
                                                 TOKENS, 4096, 2048);

  // mLSTM core (MFMA) + multi-head norm + output gate
  mlstm_mfma_kernel<<<dim3(32, 16), dim3(128), 0, stream>>>(qkb, vb, garr, lfc,
                                                            mxp, h);
  hout_kernel<<<TOKENS, blk, 0, stream>>>(h, obuf, mhw, houtb);

  // attn = houtb @ Wout (fp32 out)
  castT_kernel<<<dim3(64, 64), blk, 0, stream>>>(Wout, W, 2048, 2048);
  gemm_bf16<0><<<dim3(16, 16), blk, 0, stream>>>(houtb, W, attn, nullptr,
                                                 nullptr, TOKENS, 2048, 2048);

  // f1 = x + rms(attn); f1b bf16
  addrms_kernel<1><<<TOKENS, blk, 0, stream>>>(x, attn, rms1, f1, f1b);

  // MLP
  castT_kernel<<<dim3(256, 64), blk, 0, stream>>>(Wgate, W, 2048, 8192);
  gemm_bf16<1><<<dim3(64, 16), blk, 0, stream>>>(f1b, W, gbuf, nullptr, nullptr,
                                                 TOKENS, 8192, 2048);
  castT_kernel<<<dim3(256, 64), blk, 0, stream>>>(Wup, W, 2048, 8192);
  gemm_bf16<2><<<dim3(64, 16), blk, 0, stream>>>(f1b, W, actb, nullptr, gbuf,
                                                 TOKENS, 8192, 2048);
  castT_kernel<<<dim3(64, 256), blk, 0, stream>>>(Wdown, W, 8192, 2048);
  gemm_bf16<0><<<dim3(16, 16), blk, 0, stream>>>(actb, W, mlp, nullptr, nullptr,
                                                 TOKENS, 2048, 8192);

  // out = f1 + rms(mlp)
  addrms_kernel<0><<<TOKENS, blk, 0, stream>>>(f1, mlp, rms2, out, nullptr);
}